// Round 1
// baseline (114.941 us; speedup 1.0000x reference)
//
#include <hip/hip_runtime.h>

typedef __attribute__((ext_vector_type(8))) short short8;
typedef __attribute__((ext_vector_type(8))) unsigned short u16x8;
typedef __attribute__((ext_vector_type(4))) float f32x4;

#define L2E 1.44269504f

__device__ __forceinline__ unsigned short f2bf(float f){
  unsigned u = __float_as_uint(f);
  u += 0x7fffu + ((u >> 16) & 1u);
  return (unsigned short)(u >> 16);
}
__device__ __forceinline__ float bf2f(unsigned short h){
  return __uint_as_float(((unsigned)h) << 16);
}

// ---------------- prep: fold score_w through q_w / kv_w ----------------
// qv[d]  = sum_h q_w[d][h]  * wq[h],  cq = q_b.wq + score_b
// kvv[d] = sum_h kv_w[d][h] * wk[h],  ck = kv_b[:128].wk
__global__ void prep_vecs(const float* __restrict__ qw, const float* __restrict__ qb,
                          const float* __restrict__ kvw, const float* __restrict__ kvb,
                          const float* __restrict__ scw, const float* __restrict__ scb,
                          float* __restrict__ qv, float* __restrict__ kvv,
                          float* __restrict__ cqck){
  int d = threadIdx.x; // 0..127
  float a = 0.f, c = 0.f;
  for (int h = 0; h < 128; ++h){
    a = fmaf(qw[d*128 + h],  scw[h],       a);
    c = fmaf(kvw[d*256 + h], scw[128 + h], c);
  }
  qv[d] = a; kvv[d] = c;
  if (d == 0){
    float cq = scb[0], ck = 0.f;
    for (int h = 0; h < 128; ++h){
      cq = fmaf(qb[h],  scw[h],       cq);
      ck = fmaf(kvb[h], scw[128 + h], ck);
    }
    cqck[0] = cq; cqck[1] = ck;
  }
}

// W2T[ho][din] = sum_h kv_w[din][128+h] * out_w[h][ho]   (bf16, transposed)
// c2[ho] = sum_h kv_b[128+h] * out_w[h][ho] + out_b[ho]
__global__ __launch_bounds__(256) void prep_w2(const float* __restrict__ kvw,
                          const float* __restrict__ kvb,
                          const float* __restrict__ outw, const float* __restrict__ outb,
                          unsigned short* __restrict__ w2t, float* __restrict__ c2){
  int blk = blockIdx.x;
  if (blk < 64){
    int idx = blk*256 + threadIdx.x;
    int ho = idx >> 7, di = idx & 127;
    float s = 0.f;
    for (int h = 0; h < 128; ++h) s = fmaf(kvw[di*256 + 128 + h], outw[h*128 + ho], s);
    w2t[ho*128 + di] = f2bf(s);
  } else if (threadIdx.x < 128){
    int ho = threadIdx.x;
    float s = outb[ho];
    for (int h = 0; h < 128; ++h) s = fmaf(kvb[128 + h], outw[h*128 + ho], s);
    c2[ho] = s;
  }
}

// sq'[b*1024+m] = L2E * (mf[b,m,:].qv + cq)   -- one wave per row
__global__ __launch_bounds__(256) void prep_sq(const float* __restrict__ mf,
                          const float* __restrict__ qv, const float* __restrict__ cqck,
                          float* __restrict__ sqp){
  int row = blockIdx.x*4 + (threadIdx.x >> 6); // 0..8191
  int lane = threadIdx.x & 63;
  float s = mf[row*128 + lane] * qv[lane] + mf[row*128 + 64 + lane] * qv[64 + lane];
  #pragma unroll
  for (int o = 32; o; o >>= 1) s += __shfl_xor(s, o, 64);
  if (lane == 0) sqp[row] = L2E * (s + cqck[0]);
}

// sk'[b*4096+c] = L2E * (of[b,c,:].kvv + ck) ; also ofT[b][d][c] = bf16(of[b][c][d])
__global__ __launch_bounds__(256) void prep_sk_tr(const float* __restrict__ of,
                          const float* __restrict__ kvv, const float* __restrict__ cqck,
                          float* __restrict__ skp, unsigned short* __restrict__ ofT){
  __shared__ unsigned short tile[64*130];
  int b  = blockIdx.x >> 6;
  int c0 = (blockIdx.x & 63) << 6;
  int t  = threadIdx.x;
  int r  = t >> 2, dq = (t & 3) << 5;   // row 0..63, d-quarter
  const float* src = of + ((size_t)(b*4096 + c0 + r))*128 + dq;
  float part = 0.f;
  #pragma unroll
  for (int j = 0; j < 32; j += 4){
    float4 v = *(const float4*)(src + j);
    part = fmaf(v.x, kvv[dq + j],     part);
    part = fmaf(v.y, kvv[dq + j + 1], part);
    part = fmaf(v.z, kvv[dq + j + 2], part);
    part = fmaf(v.w, kvv[dq + j + 3], part);
    tile[r*130 + dq + j]     = f2bf(v.x);
    tile[r*130 + dq + j + 1] = f2bf(v.y);
    tile[r*130 + dq + j + 2] = f2bf(v.z);
    tile[r*130 + dq + j + 3] = f2bf(v.w);
  }
  part += __shfl_xor(part, 1, 64);
  part += __shfl_xor(part, 2, 64);
  if ((t & 3) == 0) skp[b*4096 + c0 + r] = L2E * (part + cqck[1]);
  __syncthreads();
  int d = t >> 1, chh = (t & 1) << 5;
  unsigned short* dst = ofT + ((size_t)(b*128 + d))*4096 + c0 + chh;
  #pragma unroll
  for (int j = 0; j < 32; j += 8){
    u16x8 v;
    #pragma unroll
    for (int k = 0; k < 8; ++k) v[k] = tile[(chh + j + k)*130 + d];
    *(u16x8*)(dst + j) = v;
  }
}

// ---------------- main fused kernel ----------------
// grid 512: b = blk>>6, m-tile of 16 rows. 4 waves; wave w owns of-dims [w*32, w*32+32).
// Per C-chunk of 256: all threads compute P (bf16, XOR-swizzled) into LDS, one barrier,
// then MFMA P(16x256) @ ofT-chunk(256x128) accumulating ACC(16x128).
// Epilogue: rowsum reduce, ACC->LDS bf16, (16x128)@W2(128x128), /rowsum + c2, store f32.
__global__ __launch_bounds__(256) void attn_main(
    const float* __restrict__ mask, const float* __restrict__ sqp,
    const float* __restrict__ skp, const unsigned short* __restrict__ ofT,
    const unsigned short* __restrict__ w2t, const float* __restrict__ c2,
    float* __restrict__ out)
{
  __shared__ unsigned short Pl[2][16*256];
  __shared__ unsigned short A2[16*128];
  __shared__ float rs[16];
  const int blk = blockIdx.x;
  const int b  = blk >> 6;
  const int m0 = (blk & 63) << 4;
  const int t  = threadIdx.x;
  const int w  = t >> 6;
  const int l  = t & 63;
  const int l15 = l & 15, l4 = l >> 4;

  // P-phase mapping: row r (0..15), 16 consecutive c per thread
  const int r = t >> 4;
  const int csub = (t & 15) << 4;
  const int xr = (r & 7) << 4;
  const float* mrow  = mask + ((size_t)(b*1024 + m0 + r))*4096 + csub;
  const float* skrow = skp + b*4096 + csub;
  const float sqv = sqp[b*1024 + m0 + r];

  // B operand bases (ofT is (b,128,4096) bf16; L2-resident)
  const unsigned short* bp0 = ofT + ((size_t)(b*128 + w*32 + l15))*4096 + l4*8;
  const unsigned short* bp1 = bp0 + 16*4096;

  f32x4 acc0 = {0.f,0.f,0.f,0.f}, acc1 = {0.f,0.f,0.f,0.f};
  float rsum = 0.f;

  for (int ch = 0; ch < 16; ++ch){
    const int cb = ch << 8;
    float4 mv[4], sv[4];
    #pragma unroll
    for (int i = 0; i < 4; ++i){
      mv[i] = *(const float4*)(mrow + cb + i*4);
      sv[i] = *(const float4*)(skrow + cb + i*4);
    }
    float pvals[16];
    #pragma unroll
    for (int i = 0; i < 4; ++i){
      float sx[4] = {sv[i].x, sv[i].y, sv[i].z, sv[i].w};
      float mx[4] = {mv[i].x, mv[i].y, mv[i].z, mv[i].w};
      #pragma unroll
      for (int j = 0; j < 4; ++j){
        float s = sqv + sx[j];            // log2-domain (pre-scaled by L2E)
        s = fmaxf(s, 0.01f*s);            // leaky (positively homogeneous)
        s *= mx[j];                       // mask: 0 -> exp2(0)=1
        pvals[i*4 + j] = __builtin_amdgcn_exp2f(s);
      }
    }
    u16x8 plo, phi;
    #pragma unroll
    for (int j = 0; j < 8; ++j){
      unsigned short h0 = f2bf(pvals[j]), h1 = f2bf(pvals[8 + j]);
      plo[j] = h0; phi[j] = h1;
      rsum += bf2f(h0) + bf2f(h1);        // denominator matches bf16-rounded numerator
    }
    char* base = (char*)&Pl[ch & 1][0] + r*512;
    *(u16x8*)(base + ((csub*2)      ^ xr)) = plo;
    *(u16x8*)(base + ((csub*2 + 16) ^ xr)) = phi;
    __syncthreads();
    const char* abase = (const char*)&Pl[ch & 1][0] + l15*512;
    const int xa = (l15 & 7) << 4;
    #pragma unroll
    for (int ks = 0; ks < 8; ++ks){
      short8 afrag = *(const short8*)(abase + ((ks*64 + l4*16) ^ xa));
      short8 bfr0  = *(const short8*)(bp0 + cb + ks*32);
      short8 bfr1  = *(const short8*)(bp1 + cb + ks*32);
      acc0 = __builtin_amdgcn_mfma_f32_16x16x32_bf16(afrag, bfr0, acc0, 0, 0, 0);
      acc1 = __builtin_amdgcn_mfma_f32_16x16x32_bf16(afrag, bfr1, acc1, 0, 0, 0);
    }
    // no second barrier: double-buffered; next write goes to other buffer and is
    // ordered after this chunk's barrier for all waves.
  }
  // rowsum: threads t = r*16 + i share a row -> reduce within 16-lane groups
  rsum += __shfl_xor(rsum, 1, 64);
  rsum += __shfl_xor(rsum, 2, 64);
  rsum += __shfl_xor(rsum, 4, 64);
  rsum += __shfl_xor(rsum, 8, 64);
  if ((t & 15) == 0) rs[r] = rsum;
  // ACC -> LDS bf16 (swizzled). D layout: row = l4*4+j, col = w*32 + n*16 + l15
  #pragma unroll
  for (int n = 0; n < 2; ++n){
    const f32x4 a = n ? acc1 : acc0;
    const int col = w*32 + n*16 + l15;
    #pragma unroll
    for (int j = 0; j < 4; ++j){
      const int row = l4*4 + j;
      *(unsigned short*)((char*)A2 + row*256 + ((col*2) ^ ((row & 7) << 4))) = f2bf(a[j]);
    }
  }
  __syncthreads();
  // GEMM2: OUT(16 x 128) = A2 @ W2 ; wave w -> output cols [w*32, w*32+32)
  f32x4 o0 = {0.f,0.f,0.f,0.f}, o1 = {0.f,0.f,0.f,0.f};
  const unsigned short* wp0 = w2t + (size_t)(w*32 + l15)*128 + l4*8;
  const unsigned short* wp1 = wp0 + 16*128;
  const char* a2b = (const char*)A2 + l15*256;
  const int xa2 = (l15 & 7) << 4;
  #pragma unroll
  for (int ks = 0; ks < 4; ++ks){
    short8 afrag = *(const short8*)(a2b + ((ks*64 + l4*16) ^ xa2));
    short8 b0 = *(const short8*)(wp0 + ks*32);
    short8 b1 = *(const short8*)(wp1 + ks*32);
    o0 = __builtin_amdgcn_mfma_f32_16x16x32_bf16(afrag, b0, o0, 0, 0, 0);
    o1 = __builtin_amdgcn_mfma_f32_16x16x32_bf16(afrag, b1, o1, 0, 0, 0);
  }
  #pragma unroll
  for (int n = 0; n < 2; ++n){
    const f32x4 o = n ? o1 : o0;
    const int col = w*32 + n*16 + l15;
    const float cc = c2[col];
    #pragma unroll
    for (int j = 0; j < 4; ++j){
      const int row = l4*4 + j;
      out[((size_t)(b*1024 + m0 + row))*128 + col] = o[j] / rs[row] + cc;
    }
  }
}

extern "C" void kernel_launch(void* const* d_in, const int* in_sizes, int n_in,
                              void* d_out, int out_size, void* d_ws, size_t ws_size,
                              hipStream_t stream){
  const float* of   = (const float*)d_in[0];   // (8,4096,128)
  const float* mf   = (const float*)d_in[1];   // (8,1024,128)
  const float* mask = (const float*)d_in[2];   // (8,1024,4096)
  const float* qw   = (const float*)d_in[3];
  const float* qb   = (const float*)d_in[4];
  const float* kvw  = (const float*)d_in[5];
  const float* kvb  = (const float*)d_in[6];
  const float* scw  = (const float*)d_in[7];
  const float* scb  = (const float*)d_in[8];
  const float* outw = (const float*)d_in[9];
  const float* outb = (const float*)d_in[10];
  float* out = (float*)d_out;

  char* ws = (char*)d_ws;
  unsigned short* ofT  = (unsigned short*)(ws);             // 8 MiB bf16 (8,128,4096)
  unsigned short* w2t  = (unsigned short*)(ws + 8388608);   // 32 KiB bf16 (128,128)
  float* c2   = (float*)(ws + 8421376);                     // 512 B
  float* sqp  = (float*)(ws + 8421888);                     // 32 KiB
  float* skp  = (float*)(ws + 8454656);                     // 128 KiB
  float* qv   = (float*)(ws + 8585728);                     // 512 B
  float* kvv  = (float*)(ws + 8586240);                     // 512 B
  float* cqck = (float*)(ws + 8586752);                     // 8 B

  prep_vecs<<<1, 128, 0, stream>>>(qw, qb, kvw, kvb, scw, scb, qv, kvv, cqck);
  prep_w2<<<65, 256, 0, stream>>>(kvw, kvb, outw, outb, w2t, c2);
  prep_sq<<<2048, 256, 0, stream>>>(mf, qv, cqck, sqp);
  prep_sk_tr<<<512, 256, 0, stream>>>(of, kvv, cqck, skp, ofT);
  attn_main<<<512, 256, 0, stream>>>(mask, sqp, skp, ofT, w2t, c2, out);
}